// Round 1
// baseline (320.955 us; speedup 1.0000x reference)
//
#include <hip/hip_runtime.h>
#include <hip/hip_bf16.h>
#include <math.h>

#define BB 512
#define DD 128
#define CC 100000

#define BLK_M 64
#define BLK_N 128
#define LDA (DD + 8)   // +8 bf16 pad: row stride 272B = 68 words -> 2-way bank aliasing (free)
#define LDB (DD + 8)

__device__ __constant__ const float COS_M  =  0.87758256189037271612f;  // cos(0.5)
__device__ __constant__ const float SIN_M  =  0.47942553860420300538f;  // sin(0.5)
__device__ __constant__ const float THRESH = -0.87758256189037271612f;  // cos(pi-0.5)
__device__ __constant__ const float MMc    =  0.23971276930210150269f;  // sin(0.5)*0.5
#define SCALE_F 64.0f
#define ALPHA_F 1.2f

typedef __attribute__((ext_vector_type(8))) short short8;
typedef __attribute__((ext_vector_type(4))) float float4v;

__device__ inline float waveReduceSum(float v) {
    #pragma unroll
    for (int off = 32; off > 0; off >>= 1)
        v += __shfl_xor(v, off, 64);
    return v;
}

// --- K1: L2-normalize feats rows -> bf16 ---
__global__ void k_norm_feats(const float* __restrict__ feats, __hip_bfloat16* __restrict__ exb) {
    int row = blockIdx.x;
    int lane = threadIdx.x;  // 64 threads, 2 floats each
    float2 v = ((const float2*)(feats + row * DD))[lane];
    float ss = waveReduceSum(v.x * v.x + v.y * v.y);
    float rn = rsqrtf(ss);
    __hip_bfloat162 o;
    o.x = __float2bfloat16(v.x * rn);
    o.y = __float2bfloat16(v.y * rn);
    ((__hip_bfloat162*)(exb + row * DD))[lane] = o;
}

// --- K2a: L2-normalize weight rows -> bf16 (fast path, needs 25.6 MB ws) ---
__global__ void k_norm_w(const float* __restrict__ w, __hip_bfloat16* __restrict__ ewb) {
    int wave = threadIdx.x >> 6;
    int lane = threadIdx.x & 63;
    size_t row = (size_t)blockIdx.x * 4 + wave;
    float2 v = ((const float2*)(w + row * DD))[lane];
    float ss = waveReduceSum(v.x * v.x + v.y * v.y);
    float rn = rsqrtf(ss);
    __hip_bfloat162 o;
    o.x = __float2bfloat16(v.x * rn);
    o.y = __float2bfloat16(v.y * rn);
    ((__hip_bfloat162*)(ewb + row * DD))[lane] = o;
}

// --- K2b: inverse norms only (compact-ws fallback) ---
__global__ void k_winv(const float* __restrict__ w, float* __restrict__ winv) {
    int wave = threadIdx.x >> 6;
    int lane = threadIdx.x & 63;
    size_t row = (size_t)blockIdx.x * 4 + wave;
    float2 v = ((const float2*)(w + row * DD))[lane];
    float ss = waveReduceSum(v.x * v.x + v.y * v.y);
    if (lane == 0) winv[row] = rsqrtf(ss);
}

// --- K3: per-row a_lb in full fp32 ---
__global__ void k_alb(const float* __restrict__ feats, const float* __restrict__ w,
                      const int* __restrict__ labels, float* __restrict__ alb) {
    int b = blockIdx.x;
    int lane = threadIdx.x;
    int lab = labels[b];
    float2 f = ((const float2*)(feats + b * DD))[lane];
    float2 g = ((const float2*)(w + (size_t)lab * DD))[lane];
    float dot = waveReduceSum(f.x * g.x + f.y * g.y);
    float nf  = waveReduceSum(f.x * f.x + f.y * f.y);
    float nw  = waveReduceSum(g.x * g.x + g.y * g.y);
    if (lane == 0) {
        float c = dot * rsqrtf(nf * nw);
        float a;
        if (c > THRESH) {
            float cc = fminf(fmaxf(c, -1.0f), 1.0f);
            // cos(acos(cc) + M) = cc*cosM - sinM*sqrt(1-cc^2)
            a = cc * COS_M - SIN_M * sqrtf(fmaxf(0.0f, 1.0f - cc * cc));
        } else {
            a = c - MMc;
        }
        alb[b] = a;
    }
}

// --- K4: fused bf16-MFMA GEMM + ArcNegFace epilogue ---
// tile 64 rows x 128 cols, 256 threads (4 waves), K=128 fully resident in LDS
template <bool PRE>
__global__ __launch_bounds__(256, 3)
void k_main(const __hip_bfloat16* __restrict__ exb,
            const void* __restrict__ Bsrc,          // PRE: ewb bf16 [C][128]; else w f32 [C][128]
            const float* __restrict__ winv,
            const float* __restrict__ alb,
            const int* __restrict__ labels,
            float* __restrict__ out) {
    __shared__ __hip_bfloat16 As[BLK_M][LDA];   // 17408 B
    __shared__ __hip_bfloat16 Bs[BLK_N][LDB];   // 34816 B

    int tid = threadIdx.x;
    int cb = blockIdx.x;   // column block (classes)
    int rb = blockIdx.y;   // row block (batch)

    // stage A: 64x128 bf16 = 1024 x uint4
    {
        const uint4* src = (const uint4*)(exb + (size_t)rb * BLK_M * DD);
        #pragma unroll
        for (int i = tid; i < BLK_M * DD / 8; i += 256) {
            int r = i >> 4, kc = i & 15;
            uint4 v = src[i];
            *(uint4*)(&As[r][kc * 8]) = v;
        }
    }
    // stage B: 128x128 bf16
    if (PRE) {
        const uint4* src = (const uint4*)((const __hip_bfloat16*)Bsrc + (size_t)cb * BLK_N * DD);
        #pragma unroll
        for (int i = tid; i < BLK_N * DD / 8; i += 256) {
            int r = i >> 4, kc = i & 15;
            int c = cb * BLK_N + r;
            uint4 v = make_uint4(0u, 0u, 0u, 0u);
            if (c < CC) v = src[i];
            *(uint4*)(&Bs[r][kc * 8]) = v;
        }
    } else {
        const float* wsrc = (const float*)Bsrc;
        #pragma unroll
        for (int i = tid; i < BLK_N * DD / 4; i += 256) {
            int r = i >> 5, kc = i & 31;
            int c = cb * BLK_N + r;
            float4 v = make_float4(0.f, 0.f, 0.f, 0.f);
            float rn = 0.f;
            if (c < CC) { v = ((const float4*)(wsrc + (size_t)c * DD))[kc]; rn = winv[c]; }
            __hip_bfloat16* dst = &Bs[r][kc * 4];
            dst[0] = __float2bfloat16(v.x * rn);
            dst[1] = __float2bfloat16(v.y * rn);
            dst[2] = __float2bfloat16(v.z * rn);
            dst[3] = __float2bfloat16(v.w * rn);
        }
    }
    __syncthreads();

    int wave = tid >> 6;
    int lane = tid & 63;
    int lrow = lane & 15;    // A/B: m/n index; C/D: col index
    int lquad = lane >> 4;   // A/B: k-chunk; C/D: row group

    float4v acc[4][2];
    #pragma unroll
    for (int i = 0; i < 4; i++)
        #pragma unroll
        for (int j = 0; j < 2; j++) acc[i][j] = (float4v)(0.0f);

    #pragma unroll
    for (int ks = 0; ks < 4; ks++) {
        int k0 = ks * 32 + lquad * 8;
        short8 af[4], bf[2];
        #pragma unroll
        for (int mt = 0; mt < 4; mt++)
            af[mt] = *(const short8*)(&As[mt * 16 + lrow][k0]);
        #pragma unroll
        for (int nt = 0; nt < 2; nt++)
            bf[nt] = *(const short8*)(&Bs[wave * 32 + nt * 16 + lrow][k0]);
        #pragma unroll
        for (int mt = 0; mt < 4; mt++)
            #pragma unroll
            for (int nt = 0; nt < 2; nt++)
                acc[mt][nt] = __builtin_amdgcn_mfma_f32_16x16x32_bf16(af[mt], bf[nt], acc[mt][nt], 0, 0, 0);
    }

    // epilogue: out = SCALE*( onehot*a + (1-onehot)*(rw*cos + rw - 1) ),
    // rw = ALPHA*exp(-(cos-a)^2/2)
    #pragma unroll
    for (int mt = 0; mt < 4; mt++) {
        #pragma unroll
        for (int reg = 0; reg < 4; reg++) {
            int b = rb * BLK_M + mt * 16 + lquad * 4 + reg;
            float a = alb[b];
            int lab = labels[b];
            #pragma unroll
            for (int nt = 0; nt < 2; nt++) {
                int c = cb * BLK_N + wave * 32 + nt * 16 + lrow;
                float cosv = acc[mt][nt][reg];
                float d = cosv - a;
                float rw = ALPHA_F * __expf(-0.5f * d * d);
                float val = (c == lab) ? SCALE_F * a : SCALE_F * (rw * cosv + rw - 1.0f);
                if (c < CC) out[(size_t)b * CC + c] = val;
            }
        }
    }
}

extern "C" void kernel_launch(void* const* d_in, const int* in_sizes, int n_in,
                              void* d_out, int out_size, void* d_ws, size_t ws_size,
                              hipStream_t stream) {
    const float* feats  = (const float*)d_in[0];
    const int*   labels = (const int*)d_in[1];
    const float* weight = (const float*)d_in[2];
    float* out = (float*)d_out;

    char* ws = (char*)d_ws;
    __hip_bfloat16* exb = (__hip_bfloat16*)ws;            // 512*128*2 = 131072 B
    float* alb = (float*)(ws + 131072);                   // 2048 B
    const size_t off2 = 133120;                           // 16B-aligned
    const size_t ewb_bytes = (size_t)CC * DD * 2;         // 25.6 MB

    hipLaunchKernelGGL(k_norm_feats, dim3(BB), dim3(64), 0, stream, feats, exb);
    hipLaunchKernelGGL(k_alb, dim3(BB), dim3(64), 0, stream, feats, weight, labels, alb);

    dim3 grid((CC + BLK_N - 1) / BLK_N, BB / BLK_M);      // 782 x 8

    if (ws_size >= off2 + ewb_bytes) {
        __hip_bfloat16* ewb = (__hip_bfloat16*)(ws + off2);
        hipLaunchKernelGGL(k_norm_w, dim3(CC / 4), dim3(256), 0, stream, weight, ewb);
        hipLaunchKernelGGL(k_main<true>, grid, dim3(256), 0, stream,
                           exb, (const void*)ewb, (const float*)nullptr, alb, labels, out);
    } else {
        float* winv = (float*)(ws + off2);                // 400 KB
        hipLaunchKernelGGL(k_winv, dim3(CC / 4), dim3(256), 0, stream, weight, winv);
        hipLaunchKernelGGL(k_main<false>, grid, dim3(256), 0, stream,
                           exb, (const void*)weight, winv, alb, labels, out);
    }
}

// Round 2
// 310.438 us; speedup vs baseline: 1.0339x; 1.0339x over previous
//
#include <hip/hip_runtime.h>
#include <hip/hip_bf16.h>
#include <math.h>

#define BB 512
#define DD 128
#define CC 100000

#define BLK_M 64
#define BLK_N 128
#define LDA (DD + 8)   // row stride 272B = 68 words: MFMA b128 read pattern is bank-balanced
#define LDB (DD + 8)

__device__ __constant__ const float COS_M  =  0.87758256189037271612f;  // cos(0.5)
__device__ __constant__ const float SIN_M  =  0.47942553860420300538f;  // sin(0.5)
__device__ __constant__ const float THRESH = -0.87758256189037271612f;  // cos(pi-0.5)
__device__ __constant__ const float MMc    =  0.23971276930210150269f;  // sin(0.5)*0.5
#define SCALE_F 64.0f
#define ALPHA_F 1.2f

typedef __attribute__((ext_vector_type(8))) short short8;
typedef __attribute__((ext_vector_type(4))) float float4v;

__device__ inline float waveReduceSum(float v) {
    #pragma unroll
    for (int off = 32; off > 0; off >>= 1)
        v += __shfl_xor(v, off, 64);
    return v;
}

// --- K1: fused feats-normalize (-> bf16 exb) + per-row a_lb (full fp32) ---
__global__ void k_prep(const float* __restrict__ feats, const float* __restrict__ w,
                       const int* __restrict__ labels,
                       __hip_bfloat16* __restrict__ exb, float* __restrict__ alb) {
    int b = blockIdx.x;
    int lane = threadIdx.x;          // 64 threads, 2 floats each
    int lab = labels[b];
    float2 f = ((const float2*)(feats + b * DD))[lane];
    float2 g = ((const float2*)(w + (size_t)lab * DD))[lane];
    float nf  = waveReduceSum(f.x * f.x + f.y * f.y);
    float dot = waveReduceSum(f.x * g.x + f.y * g.y);
    float nw  = waveReduceSum(g.x * g.x + g.y * g.y);
    float rn = rsqrtf(nf);
    __hip_bfloat162 o;
    o.x = __float2bfloat16(f.x * rn);
    o.y = __float2bfloat16(f.y * rn);
    ((__hip_bfloat162*)(exb + b * DD))[lane] = o;
    if (lane == 0) {
        float c = dot * rsqrtf(nf * nw);
        float a;
        if (c > THRESH) {
            float cc = fminf(fmaxf(c, -1.0f), 1.0f);
            a = cc * COS_M - SIN_M * sqrtf(fmaxf(0.0f, 1.0f - cc * cc));  // cos(acos+M)
        } else {
            a = c - MMc;
        }
        alb[b] = a;
    }
}

// --- K2: persistent column-tile kernel ---
// 782 blocks, 256 threads (4 waves). Each block: normalize its 128 weight rows
// f32->bf16 directly into LDS (each w row read from HBM exactly once), then
// loop over all 8 row-tiles of the batch: stage A (L2-resident), MFMA, fused
// ArcNegFace epilogue with nontemporal stores.
__global__ __launch_bounds__(256, 3)
void k_main(const __hip_bfloat16* __restrict__ exb,
            const float* __restrict__ w,
            const float* __restrict__ alb,
            const int* __restrict__ labels,
            float* __restrict__ out) {
    __shared__ __hip_bfloat16 As[BLK_M][LDA];   // 17408 B
    __shared__ __hip_bfloat16 Bs[BLK_N][LDB];   // 34816 B  (total 52224 -> 3 blocks/CU)

    int tid = threadIdx.x;
    int c0 = blockIdx.x * BLK_N;

    // ---- normalize BLK_N weight rows into Bs ----
    {
        int r = tid >> 1;            // 0..127
        int h = tid & 1;             // which half-row (64 floats)
        int c = c0 + r;
        float4 buf[16];
        float ss = 0.f;
        if (c < CC) {
            const float4* src = (const float4*)(w + (size_t)c * DD + h * 64);
            #pragma unroll
            for (int j = 0; j < 16; j++) {
                buf[j] = src[j];
                ss += buf[j].x * buf[j].x + buf[j].y * buf[j].y
                    + buf[j].z * buf[j].z + buf[j].w * buf[j].w;
            }
        } else {
            #pragma unroll
            for (int j = 0; j < 16; j++) buf[j] = make_float4(0.f, 0.f, 0.f, 0.f);
        }
        float tot = ss + __shfl_xor(ss, 1, 64);   // lanes 2r,2r+1 are wave-adjacent
        float rn = (c < CC) ? rsqrtf(tot) : 0.f;
        #pragma unroll
        for (int j = 0; j < 8; j++) {
            __hip_bfloat16 tmp[8];
            float4 a = buf[2 * j], b2 = buf[2 * j + 1];
            tmp[0] = __float2bfloat16(a.x * rn);
            tmp[1] = __float2bfloat16(a.y * rn);
            tmp[2] = __float2bfloat16(a.z * rn);
            tmp[3] = __float2bfloat16(a.w * rn);
            tmp[4] = __float2bfloat16(b2.x * rn);
            tmp[5] = __float2bfloat16(b2.y * rn);
            tmp[6] = __float2bfloat16(b2.z * rn);
            tmp[7] = __float2bfloat16(b2.w * rn);
            *(uint4*)(&Bs[r][h * 64 + j * 8]) = *(const uint4*)tmp;
        }
    }

    int wave = tid >> 6;
    int lane = tid & 63;
    int lrow = lane & 15;
    int lquad = lane >> 4;

    for (int rb = 0; rb < BB / BLK_M; rb++) {
        // ---- stage A tile (64x128 bf16 = 1024 uint4) ----
        {
            const uint4* src = (const uint4*)(exb + (size_t)rb * BLK_M * DD);
            #pragma unroll
            for (int i = tid; i < BLK_M * DD / 8; i += 256) {
                int r = i >> 4, kc = i & 15;
                *(uint4*)(&As[r][kc * 8]) = src[i];
            }
        }
        __syncthreads();   // staging (and Bs on first iter) visible

        float4v acc[4][2];
        #pragma unroll
        for (int i = 0; i < 4; i++)
            #pragma unroll
            for (int j = 0; j < 2; j++) acc[i][j] = (float4v)(0.0f);

        #pragma unroll
        for (int ks = 0; ks < 4; ks++) {
            int k0 = ks * 32 + lquad * 8;
            short8 af[4], bf[2];
            #pragma unroll
            for (int mt = 0; mt < 4; mt++)
                af[mt] = *(const short8*)(&As[mt * 16 + lrow][k0]);
            #pragma unroll
            for (int nt = 0; nt < 2; nt++)
                bf[nt] = *(const short8*)(&Bs[wave * 32 + nt * 16 + lrow][k0]);
            #pragma unroll
            for (int mt = 0; mt < 4; mt++)
                #pragma unroll
                for (int nt = 0; nt < 2; nt++)
                    acc[mt][nt] = __builtin_amdgcn_mfma_f32_16x16x32_bf16(af[mt], bf[nt], acc[mt][nt], 0, 0, 0);
        }

        // ---- epilogue: out = SCALE*( onehot*a + (1-onehot)*(rw*cos + rw - 1) )
        //      rw = ALPHA*exp(-(cos-a)^2/2)
        #pragma unroll
        for (int mt = 0; mt < 4; mt++) {
            #pragma unroll
            for (int reg = 0; reg < 4; reg++) {
                int b = rb * BLK_M + mt * 16 + lquad * 4 + reg;
                float a = alb[b];
                int lab = labels[b];
                #pragma unroll
                for (int nt = 0; nt < 2; nt++) {
                    int c = c0 + wave * 32 + nt * 16 + lrow;
                    float cosv = acc[mt][nt][reg];
                    float d = cosv - a;
                    float rw = ALPHA_F * __expf(-0.5f * d * d);
                    float val = (c == lab) ? SCALE_F * a : SCALE_F * (rw * cosv + rw - 1.0f);
                    if (c < CC)
                        __builtin_nontemporal_store(val, &out[(size_t)b * CC + c]);
                }
            }
        }
        __syncthreads();   // all As reads done before next overwrite
    }
}

extern "C" void kernel_launch(void* const* d_in, const int* in_sizes, int n_in,
                              void* d_out, int out_size, void* d_ws, size_t ws_size,
                              hipStream_t stream) {
    const float* feats  = (const float*)d_in[0];
    const int*   labels = (const int*)d_in[1];
    const float* weight = (const float*)d_in[2];
    float* out = (float*)d_out;

    char* ws = (char*)d_ws;
    __hip_bfloat16* exb = (__hip_bfloat16*)ws;            // 512*128*2 = 131072 B
    float* alb = (float*)(ws + 131072);                   // 2048 B

    hipLaunchKernelGGL(k_prep, dim3(BB), dim3(64), 0, stream,
                       feats, weight, labels, exb, alb);

    dim3 grid((CC + BLK_N - 1) / BLK_N);                  // 782 persistent column blocks
    hipLaunchKernelGGL(k_main, grid, dim3(256), 0, stream,
                       exb, weight, alb, labels, out);
}

// Round 4
// 254.703 us; speedup vs baseline: 1.2601x; 1.2188x over previous
//
#include <hip/hip_runtime.h>
#include <hip/hip_bf16.h>
#include <math.h>

#define BB 512
#define DD 128
#define CC 100000

#define BLK_M 64
#define BLK_N 64
#define LDA 136                 // bf16 units; 272B row stride -> balanced b128 MFMA reads
#define LDB 136
#define LDT 68                  // f32 units for the transpose view of the A buffer

__device__ __constant__ const float COS_M  =  0.87758256189037271612f;  // cos(0.5)
__device__ __constant__ const float SIN_M  =  0.47942553860420300538f;  // sin(0.5)
__device__ __constant__ const float THRESH = -0.87758256189037271612f;  // cos(pi-0.5)
__device__ __constant__ const float MMc    =  0.23971276930210150269f;  // sin(0.5)*0.5
#define SCALE_F 64.0f
#define ALPHA_F 1.2f

typedef __attribute__((ext_vector_type(8))) short short8;
typedef __attribute__((ext_vector_type(4))) float float4v;

__device__ inline float waveReduceSum(float v) {
    #pragma unroll
    for (int off = 32; off > 0; off >>= 1)
        v += __shfl_xor(v, off, 64);
    return v;
}

// --- K1: fused feats-normalize (-> bf16 exb) + per-row a_lb (full fp32) ---
__global__ void k_prep(const float* __restrict__ feats, const float* __restrict__ w,
                       const int* __restrict__ labels,
                       __hip_bfloat16* __restrict__ exb, float* __restrict__ alb) {
    int b = blockIdx.x;
    int lane = threadIdx.x;          // 64 threads, 2 floats each
    int lab = labels[b];
    float2 f = ((const float2*)(feats + b * DD))[lane];
    float2 g = ((const float2*)(w + (size_t)lab * DD))[lane];
    float nf  = waveReduceSum(f.x * f.x + f.y * f.y);
    float dot = waveReduceSum(f.x * g.x + f.y * g.y);
    float nw  = waveReduceSum(g.x * g.x + g.y * g.y);
    float rn = rsqrtf(nf);
    __hip_bfloat162 o;
    o.x = __float2bfloat16(f.x * rn);
    o.y = __float2bfloat16(f.y * rn);
    ((__hip_bfloat162*)(exb + b * DD))[lane] = o;
    if (lane == 0) {
        float c = dot * rsqrtf(nf * nw);
        float a;
        if (c > THRESH) {
            float cc = fminf(fmaxf(c, -1.0f), 1.0f);
            a = cc * COS_M - SIN_M * sqrtf(fmaxf(0.0f, 1.0f - cc * cc));  // cos(acos+M)
        } else {
            a = c - MMc;
        }
        alb[b] = a;
    }
}

// --- K2: column-tile kernel, 64 cols per block ---
// 1563 blocks, 256 threads (4 waves), 4 blocks/CU (LDS 34,816 B).
// Per block: normalize its 64 weight rows f32->bf16 straight into LDS (each
// weight row read from HBM exactly once), then loop over the 8 batch row-
// tiles: stage A (L2-resident), MFMA, transpose the f32 tile through the A
// buffer, fused ArcNegFace epilogue, full-line dwordx4 nontemporal stores.
__global__ __launch_bounds__(256, 4)
void k_main(const __hip_bfloat16* __restrict__ exb,
            const float* __restrict__ w,
            const float* __restrict__ alb,
            const int* __restrict__ labels,
            float* __restrict__ out) {
    __shared__ __align__(16) char smemA[BLK_M * LDA * 2];      // 17408 B: bf16 A-tile, then f32 transpose
    __shared__ __align__(16) __hip_bfloat16 Bs[BLK_N][LDB];    // 17408 B

    __hip_bfloat16 (*As)[LDA] = (__hip_bfloat16(*)[LDA])smemA;
    float (*Tr)[LDT] = (float(*)[LDT])smemA;

    int tid = threadIdx.x;
    int c0 = blockIdx.x * BLK_N;

    // ---- normalize BLK_N weight rows into Bs (4 threads per row) ----
    {
        int r = tid >> 2;            // 0..63
        int h = tid & 3;             // quarter-row: 32 floats
        int c = c0 + r;
        float4 buf[8];
        float ss = 0.f;
        if (c < CC) {
            const float4* src = (const float4*)(w + (size_t)c * DD + h * 32);
            #pragma unroll
            for (int j = 0; j < 8; j++) {
                buf[j] = src[j];
                ss += buf[j].x * buf[j].x + buf[j].y * buf[j].y
                    + buf[j].z * buf[j].z + buf[j].w * buf[j].w;
            }
        } else {
            #pragma unroll
            for (int j = 0; j < 8; j++) buf[j] = make_float4(0.f, 0.f, 0.f, 0.f);
        }
        float tot = ss + __shfl_xor(ss, 1, 64);
        tot += __shfl_xor(tot, 2, 64);           // lanes 4r..4r+3 are wave-adjacent
        float rn = (c < CC) ? rsqrtf(tot) : 0.f;
        #pragma unroll
        for (int j = 0; j < 4; j++) {
            __hip_bfloat16 tmp[8];
            float4 a = buf[2 * j], b2 = buf[2 * j + 1];
            tmp[0] = __float2bfloat16(a.x * rn);
            tmp[1] = __float2bfloat16(a.y * rn);
            tmp[2] = __float2bfloat16(a.z * rn);
            tmp[3] = __float2bfloat16(a.w * rn);
            tmp[4] = __float2bfloat16(b2.x * rn);
            tmp[5] = __float2bfloat16(b2.y * rn);
            tmp[6] = __float2bfloat16(b2.z * rn);
            tmp[7] = __float2bfloat16(b2.w * rn);
            *(uint4*)(&Bs[r][h * 32 + j * 8]) = *(const uint4*)tmp;
        }
    }

    int wave = tid >> 6;
    int lane = tid & 63;
    int lrow = lane & 15;
    int lquad = lane >> 4;

    for (int rb = 0; rb < BB / BLK_M; rb++) {
        __syncthreads();   // prev-iter Tr reads done (and normalize done, iter 0)

        // ---- stage A tile (64x128 bf16 = 1024 uint4, 4 per thread) ----
        {
            const uint4* src = (const uint4*)(exb + (size_t)rb * BLK_M * DD);
            #pragma unroll
            for (int j = 0; j < 4; j++) {
                int i = tid + j * 256;
                int r = i >> 4, kc = i & 15;
                *(uint4*)(&As[r][kc * 8]) = src[i];
            }
        }
        __syncthreads();   // A staged, Bs visible

        float4v acc[4];
        #pragma unroll
        for (int i = 0; i < 4; i++) acc[i] = (float4v)(0.0f);

        #pragma unroll
        for (int ks = 0; ks < 4; ks++) {
            int k0 = ks * 32 + lquad * 8;
            short8 bf = *(const short8*)(&Bs[wave * 16 + lrow][k0]);
            #pragma unroll
            for (int mt = 0; mt < 4; mt++) {
                short8 af = *(const short8*)(&As[mt * 16 + lrow][k0]);
                acc[mt] = __builtin_amdgcn_mfma_f32_16x16x32_bf16(af, bf, acc[mt], 0, 0, 0);
            }
        }
        __syncthreads();   // all As reads done; A buffer now reusable as Tr

        // ---- write f32 tile into transpose buffer ----
        // value (mt,reg): row = mt*16 + lquad*4 + reg, col = wave*16 + lrow
        #pragma unroll
        for (int mt = 0; mt < 4; mt++)
            #pragma unroll
            for (int reg = 0; reg < 4; reg++)
                Tr[mt * 16 + lquad * 4 + reg][wave * 16 + lrow] = acc[mt][reg];
        __syncthreads();   // tile transposed

        // ---- row-major epilogue + full-line stores ----
        // out = SCALE*( onehot*a + (1-onehot)*(rw*cos + rw - 1) ), rw = ALPHA*exp(-(cos-a)^2/2)
        #pragma unroll
        for (int it = 0; it < 4; it++) {
            int flat = it * 256 + tid;          // 0..1023
            int r  = flat >> 4;                 // tile row 0..63
            int c4 = flat & 15;                 // float4 index within row
            int b = rb * BLK_M + r;
            int cbase = c0 + c4 * 4;
            if (cbase < CC) {                   // CC%4==0, c0%64==0 -> whole float4 valid
                float a = alb[b];
                int lab = labels[b];
                float4v v = *(const float4v*)(&Tr[r][c4 * 4]);
                float4v res;
                #pragma unroll
                for (int e = 0; e < 4; e++) {
                    float cosv = v[e];
                    float d = cosv - a;
                    float rw = ALPHA_F * __expf(-0.5f * d * d);
                    res[e] = (cbase + e == lab) ? SCALE_F * a
                                                : SCALE_F * (rw * cosv + rw - 1.0f);
                }
                __builtin_nontemporal_store(res, (float4v*)(out + (size_t)b * CC + cbase));
            }
        }
    }
}

extern "C" void kernel_launch(void* const* d_in, const int* in_sizes, int n_in,
                              void* d_out, int out_size, void* d_ws, size_t ws_size,
                              hipStream_t stream) {
    const float* feats  = (const float*)d_in[0];
    const int*   labels = (const int*)d_in[1];
    const float* weight = (const float*)d_in[2];
    float* out = (float*)d_out;

    char* ws = (char*)d_ws;
    __hip_bfloat16* exb = (__hip_bfloat16*)ws;            // 512*128*2 = 131072 B
    float* alb = (float*)(ws + 131072);                   // 2048 B

    hipLaunchKernelGGL(k_prep, dim3(BB), dim3(64), 0, stream,
                       feats, weight, labels, exb, alb);

    dim3 grid((CC + BLK_N - 1) / BLK_N);                  // 1563 column tiles
    hipLaunchKernelGGL(k_main, grid, dim3(256), 0, stream,
                       exb, weight, alb, labels, out);
}